// Round 7
// baseline (754.682 us; speedup 1.0000x reference)
//
#include <hip/hip_runtime.h>
#include <hip/hip_bf16.h>
#include <stdint.h>

// Problem constants (confirmed matching trace by round-6 runtime-dims run)
#define NB 32
#define NL 256
#define NS 4
#define ND 512
#define NH 1024           // NL * NS
#define FIVE_D 2560
#define HID 2048
#define MMAX 32768        // NB * NS * NL (cap on compact rows)
#define CHUNK 8192        // rows per chunk (workspace ~88 MB)
#define NCHUNK 4

// Inputs: f32 / int32. OUTPUT: f32 (states [B,S,L,D] then mask [B,S,L]).
typedef __bf16 bf16_t;
typedef __bf16 bf16x8 __attribute__((ext_vector_type(8)));
typedef float f32x4 __attribute__((ext_vector_type(4)));

// async global->LDS, 16B per lane (wave-uniform base + lane*16 layout).
// End-to-end verified correct in rounds 1-4 (DMA pipeline == fp32 pipeline).
__device__ __forceinline__ void async_ld16(const void* g, void* l) {
  __builtin_amdgcn_global_load_lds(
      (__attribute__((address_space(1))) void*)(uintptr_t)g,
      (__attribute__((address_space(3))) void*)(uintptr_t)l, 16, 0, 0);
}

// ---------------------------------------------------------------------------
// K1: build compact row index. 1 block, 128 threads = (b, s) pairs.
// ---------------------------------------------------------------------------
__global__ void build_index_kernel(const int* __restrict__ group_ids,
                                   const int* __restrict__ lengths,
                                   int* __restrict__ n_rows,
                                   int* __restrict__ kept_eff,
                                   int* __restrict__ row_src,
                                   int* __restrict__ row_dst) {
  int t = threadIdx.x;            // 0..127
  if (t == 0) *n_rows = 0;
  __syncthreads();
  int b = t >> 2, s = t & 3;
  int len = lengths[b];
  if (len < 0) len = 0;
  if (len > NH) len = NH;
  const int* g = group_ids + b * NH;
  int count = 0;
  for (int h = 0; h < len; ++h) count += (g[h] == s + 1);
  int keff = count < NL ? count : NL;
  int offset = count - keff;      // max(count - L, 0)
  kept_eff[t] = keff;
  int base = atomicAdd(n_rows, keff);
  int rank = 0;
  for (int h = 0; h < len; ++h) {
    if (g[h] == s + 1) {
      if (rank >= offset) {
        int slot = rank - offset;
        row_src[base + slot] = b * NH + h;
        row_dst[base + slot] = (b * NS + s) * NL + slot;
      }
      ++rank;
    }
  }
}

// ---------------------------------------------------------------------------
// K2: f32 [K,N] -> bf16 [N,K] tiled transpose (weights).
// ---------------------------------------------------------------------------
template <int KD, int NDIM>
__global__ void transpose_cvt_kernel(const float* __restrict__ src,
                                     bf16_t* __restrict__ dst) {
  __shared__ float tile[32][33];
  int k0 = blockIdx.y * 32, n0 = blockIdx.x * 32;
  int tx = threadIdx.x & 31, ty = threadIdx.x >> 5;   // 32 x 8
#pragma unroll
  for (int i = 0; i < 32; i += 8)
    tile[ty + i][tx] = src[(size_t)(k0 + ty + i) * NDIM + n0 + tx];
  __syncthreads();
#pragma unroll
  for (int i = 0; i < 32; i += 8)
    dst[(size_t)(n0 + ty + i) * KD + k0 + tx] = (bf16_t)tile[tx][ty + i];
}

// ---------------------------------------------------------------------------
// K3: gather 5 f32 embeddings + LayerNorm -> bf16 X[r_local, 2560]
// One block (256 threads) per compact row in this chunk.
// ---------------------------------------------------------------------------
__global__ void gather_ln_kernel(const float* __restrict__ embed,
                                 const float* __restrict__ tg_emb,
                                 const int* __restrict__ ht,
                                 const int* __restrict__ pt,
                                 const int* __restrict__ at,
                                 const int* __restrict__ ct,
                                 const int* __restrict__ tg,
                                 const float* __restrict__ gamma,
                                 const float* __restrict__ beta,
                                 const int* __restrict__ n_rows,
                                 const int* __restrict__ row_src,
                                 int row_base,
                                 bf16_t* __restrict__ X) {
  int rl = blockIdx.x;
  int r = row_base + rl;
  if (r >= *n_rows) return;
  int pos = row_src[r];
  int t = threadIdx.x;

  const float* seg[5];
  seg[0] = embed + (size_t)ht[pos] * ND;
  seg[1] = embed + (size_t)pt[pos] * ND;
  seg[2] = embed + (size_t)at[pos] * ND;
  seg[3] = embed + (size_t)ct[pos] * ND;
  int tgv = tg[pos];
  tgv = tgv < 0 ? 0 : (tgv > 128 ? 128 : tgv);
  seg[4] = tg_emb + (size_t)tgv * ND;

  float v[10];
  float sum = 0.f, sq = 0.f;
#pragma unroll
  for (int i = 0; i < 10; ++i) {
    int c = t + i * 256;                 // 0..2559; c>>9 constant per i
    v[i] = seg[c >> 9][c & 511];
    sum += v[i];
    sq += v[i] * v[i];
  }
#pragma unroll
  for (int off = 32; off > 0; off >>= 1) {
    sum += __shfl_down(sum, off);
    sq += __shfl_down(sq, off);
  }
  __shared__ float red[8];
  int wv = t >> 6, ln = t & 63;
  if (ln == 0) { red[wv] = sum; red[4 + wv] = sq; }
  __syncthreads();
  float S = red[0] + red[1] + red[2] + red[3];
  float Q = red[4] + red[5] + red[6] + red[7];
  float mu = S * (1.f / FIVE_D);
  float var = Q * (1.f / FIVE_D) - mu * mu;
  float rstd = rsqrtf(var + 1e-5f);

  bf16_t* xr = X + (size_t)rl * FIVE_D;
#pragma unroll
  for (int i = 0; i < 10; ++i) {
    int c = t + i * 256;
    xr[c] = (bf16_t)((v[i] - mu) * rstd * gamma[c] + beta[c]);
  }
}

// ---------------------------------------------------------------------------
// MFMA GEMM (m97 structure): C[M,N] = A[M,KD] @ Bt[N,KD]^T.
// global_load_lds DMA staging, 128x128 tile, BK=32, 4 waves, 16x16x32 bf16.
// EPI=1: +bias, SiLU -> bf16 Cb[rows][LDC].
// EPI=2: +bias +pos_emb +seq_emb, scatter f32 rows via row_dst into out.
// ---------------------------------------------------------------------------
template <int KD, int LDC, int EPI>
__launch_bounds__(256)
__global__ void gemm_kernel(const bf16_t* __restrict__ A,
                            const bf16_t* __restrict__ Bt,
                            const int* __restrict__ nrows_p,
                            int row_base,
                            const float* __restrict__ bias,
                            bf16_t* __restrict__ Cb,
                            const int* __restrict__ row_dst,
                            const float* __restrict__ pos_emb,
                            const float* __restrict__ seq_emb,
                            float* __restrict__ out) {
  const int M = *nrows_p;
  const int m0 = blockIdx.y * 128;                 // local row base
  if (row_base + m0 >= M) return;
  const int n0 = blockIdx.x * 128;

  __shared__ bf16_t As[128 * 32];
  __shared__ bf16_t Bs[128 * 32];

  const int t = threadIdx.x;
  const int lane = t & 63;
  const int wave = t >> 6;
  const int wm = wave >> 1;
  const int wn = wave & 1;
  const int l15 = lane & 15;
  const int l4 = lane >> 4;

  f32x4 acc[4][4] = {};

  const int r0 = t >> 2;            // tile row for this thread's 16B segment
  const int kq = (t & 3) * 8;       // bf16 offset within 32-wide k window
  const bf16_t* Ag0 = A + (size_t)(m0 + r0) * KD + kq;
  const bf16_t* Ag1 = A + (size_t)(m0 + 64 + r0) * KD + kq;
  const bf16_t* Bg0 = Bt + (size_t)(n0 + r0) * KD + kq;
  const bf16_t* Bg1 = Bt + (size_t)(n0 + 64 + r0) * KD + kq;
  bf16_t* Al0 = As + t * 8;
  bf16_t* Al1 = As + (t + 256) * 8;
  bf16_t* Bl0 = Bs + t * 8;
  bf16_t* Bl1 = Bs + (t + 256) * 8;

  for (int k0 = 0; k0 < KD; k0 += 32) {
    __syncthreads();
    async_ld16(Ag0 + k0, Al0);
    async_ld16(Ag1 + k0, Al1);
    async_ld16(Bg0 + k0, Bl0);
    async_ld16(Bg1 + k0, Bl1);
    __syncthreads();

    bf16x8 af[4], bfr[4];
#pragma unroll
    for (int i = 0; i < 4; ++i)
      af[i] = *(const bf16x8*)(As + (wm * 64 + i * 16 + l15) * 32 + l4 * 8);
#pragma unroll
    for (int i = 0; i < 4; ++i)
      bfr[i] = *(const bf16x8*)(Bs + (wn * 64 + i * 16 + l15) * 32 + l4 * 8);
#pragma unroll
    for (int i = 0; i < 4; ++i)
#pragma unroll
      for (int j = 0; j < 4; ++j)
        acc[i][j] =
            __builtin_amdgcn_mfma_f32_16x16x32_bf16(af[i], bfr[j], acc[i][j], 0, 0, 0);
  }

  if constexpr (EPI == 1) {
#pragma unroll
    for (int i = 0; i < 4; ++i) {
      int mbase = m0 + wm * 64 + i * 16 + l4 * 4;   // local row
#pragma unroll
      for (int j = 0; j < 4; ++j) {
        int n = n0 + wn * 64 + j * 16 + l15;
        float bn = bias[n];
#pragma unroll
        for (int q = 0; q < 4; ++q) {
          float v = acc[i][j][q] + bn;
          v = v / (1.f + __expf(-v));              // SiLU
          Cb[(size_t)(mbase + q) * LDC + n] = (bf16_t)v;
        }
      }
    }
  } else {
#pragma unroll
    for (int i = 0; i < 4; ++i) {
      int mbase = m0 + wm * 64 + i * 16 + l4 * 4;   // local row
#pragma unroll
      for (int q = 0; q < 4; ++q) {
        int r = mbase + q;                          // local row
        if (row_base + r >= M) continue;
        int dst = row_dst[row_base + r];            // (b*S+s)*L + slot
        int slot = dst & (NL - 1);
        int sg = (dst >> 8) & 3;
#pragma unroll
        for (int j = 0; j < 4; ++j) {
          int n = n0 + wn * 64 + j * 16 + l15;
          float v = acc[i][j][q] + bias[n] + pos_emb[slot * ND + n] +
                    seq_emb[(sg + 1) * ND + n];
          out[(size_t)dst * ND + n] = v;            // f32 output
        }
      }
    }
  }
}

// ---------------------------------------------------------------------------
// K5: background fill (f32) — zeros for unkept slots, empty-group slot 0,
// and the f32 sequence mask. One block per (b, s).
// ---------------------------------------------------------------------------
__global__ void fill_bg_kernel(const int* __restrict__ kept_eff,
                               const float* __restrict__ empty_tokens,
                               const float* __restrict__ pos_emb,
                               const float* __restrict__ seq_emb,
                               float* __restrict__ out,
                               float* __restrict__ mask) {
  int g = blockIdx.x;              // b*S + s
  int s = g & 3;
  int t = threadIdx.x;
  int ce = kept_eff[g];            // min(count, L)
  bool empty = (ce == 0);
  int keptm = empty ? 1 : ce;

  mask[g * NL + t] = (t < keptm) ? 1.f : 0.f;      // t in [0,256)=L

  float* base = out + (size_t)g * NL * ND;
  if (empty) {
    for (int d = t; d < ND; d += 256)
      base[d] = empty_tokens[s * ND + d] + pos_emb[d] + seq_emb[(s + 1) * ND + d];
  }
  int start = empty ? 1 : ce;
  // zero-fill slots [start, 256) with 16B stores (ND*4B per slot, 16B-aligned)
  uint4* p = (uint4*)base;         // 4 f32 per uint4; one slot = 128 uint4
  uint4 z; z.x = z.y = z.z = z.w = 0u;
  for (int i = start * (ND / 4) + t; i < NL * (ND / 4); i += 256) p[i] = z;
}

// ---------------------------------------------------------------------------
extern "C" void kernel_launch(void* const* d_in, const int* in_sizes, int n_in,
                              void* d_out, int out_size, void* d_ws,
                              size_t ws_size, hipStream_t stream) {
  const float* embed_table = (const float*)d_in[0];
  const float* time_gap_emb = (const float*)d_in[1];
  const float* seq_id_emb = (const float*)d_in[2];
  const float* pos_emb = (const float*)d_in[3];
  const float* ln_gamma = (const float*)d_in[4];
  const float* ln_beta = (const float*)d_in[5];
  const float* w1 = (const float*)d_in[6];
  const float* b1 = (const float*)d_in[7];
  const float* w2 = (const float*)d_in[8];
  const float* b2 = (const float*)d_in[9];
  const float* empty_tokens = (const float*)d_in[10];
  const int* history_tokens = (const int*)d_in[11];
  const int* post_tokens = (const int*)d_in[12];
  const int* author_tokens = (const int*)d_in[13];
  const int* action_tokens = (const int*)d_in[14];
  const int* time_gap = (const int*)d_in[15];
  const int* group_ids = (const int*)d_in[16];
  const int* lengths = (const int*)d_in[17];

  // Workspace (~88 MB peak)
  char* ws = (char*)d_ws;
  int* n_rows = (int*)ws;                                  // 4 B
  int* kept_eff = (int*)(ws + 256);                        // 128*4 B
  int* row_src = (int*)(ws + 4096);                        // 32768*4 B
  int* row_dst = (int*)(ws + 4096 + 131072);               // 32768*4 B
  bf16_t* W1T = (bf16_t*)(ws + 266240);                    // [2048][2560] bf16
  bf16_t* W2T = W1T + (size_t)HID * FIVE_D;                // [512][2048]  bf16
  bf16_t* Xc = W2T + (size_t)ND * HID;                     // [CHUNK][2560] bf16
  bf16_t* H1c = Xc + (size_t)CHUNK * FIVE_D;               // [CHUNK][2048] bf16

  float* out_states = (float*)d_out;                       // f32 output!
  float* out_mask = out_states + (size_t)NB * NS * NL * ND;

  build_index_kernel<<<1, 128, 0, stream>>>(group_ids, lengths, n_rows,
                                            kept_eff, row_src, row_dst);

  transpose_cvt_kernel<FIVE_D, HID>
      <<<dim3(HID / 32, FIVE_D / 32), 256, 0, stream>>>(w1, W1T);
  transpose_cvt_kernel<HID, ND>
      <<<dim3(ND / 32, HID / 32), 256, 0, stream>>>(w2, W2T);

  for (int c = 0; c < NCHUNK; ++c) {
    int row_base = c * CHUNK;
    gather_ln_kernel<<<CHUNK, 256, 0, stream>>>(
        embed_table, time_gap_emb, history_tokens, post_tokens, author_tokens,
        action_tokens, time_gap, ln_gamma, ln_beta, n_rows, row_src, row_base,
        Xc);

    gemm_kernel<FIVE_D, HID, 1>
        <<<dim3(HID / 128, CHUNK / 128), 256, 0, stream>>>(
            Xc, W1T, n_rows, row_base, b1, H1c, nullptr, nullptr, nullptr,
            nullptr);

    gemm_kernel<HID, ND, 2>
        <<<dim3(ND / 128, CHUNK / 128), 256, 0, stream>>>(
            H1c, W2T, n_rows, row_base, b2, nullptr, row_dst, pos_emb,
            seq_id_emb, out_states);
  }

  fill_bg_kernel<<<NB * NS, 256, 0, stream>>>(kept_eff, empty_tokens, pos_emb,
                                              seq_id_emb, out_states, out_mask);
}

// Round 8
// 528.928 us; speedup vs baseline: 1.4268x; 1.4268x over previous
//
#include <hip/hip_runtime.h>
#include <hip/hip_bf16.h>
#include <stdint.h>

// Problem constants
#define NB 32
#define NL 256
#define NS 4
#define ND 512
#define NH 1024           // NL * NS
#define FIVE_D 2560
#define HID 2048
#define MMAX 32768        // NB * NS * NL (cap on compact rows)
#define CHUNK 8192        // rows per chunk (workspace ~88 MB)
#define NCHUNK 4

// Inputs: f32 / int32. OUTPUT: f32 (states [B,S,L,D] then mask [B,S,L]).
typedef __bf16 bf16_t;
typedef __bf16 bf16x8 __attribute__((ext_vector_type(8)));
typedef float f32x4 __attribute__((ext_vector_type(4)));

// async global->LDS, 16B per lane (wave-uniform base + lane*16 layout).
__device__ __forceinline__ void async_ld16(const void* g, void* l) {
  __builtin_amdgcn_global_load_lds(
      (__attribute__((address_space(1))) void*)(uintptr_t)g,
      (__attribute__((address_space(3))) void*)(uintptr_t)l, 16, 0, 0);
}

// ---------------------------------------------------------------------------
// K1: build compact row index — PARALLEL version.
// One block per (b, s) group; 256 threads; ballot-based rank computation.
// (v7's 1-block serial version was the top dispatch at ~240 us, 0.02% occ.)
// ---------------------------------------------------------------------------
__global__ void build_index_kernel(const int* __restrict__ group_ids,
                                   const int* __restrict__ lengths,
                                   int* __restrict__ n_rows,
                                   int* __restrict__ kept_eff,
                                   int* __restrict__ row_src,
                                   int* __restrict__ row_dst) {
  const int g = blockIdx.x;            // b*NS + s
  const int b = g >> 2, s = g & 3;
  const int t = threadIdx.x;           // 0..255
  const int lane = t & 63, w = t >> 6; // 4 waves
  int len = lengths[b];
  len = len < 0 ? 0 : (len > NH ? NH : len);
  const int* gi = group_ids + b * NH;

  __shared__ int wtot[16];             // per (chunk, wave) match counts
  __shared__ int sbase;

  // Pass 1: per-(chunk,wave) totals via ballot popcount.
  bool valid[4];
#pragma unroll
  for (int c = 0; c < 4; ++c) {
    int h = c * 256 + t;
    valid[c] = (h < len) && (gi[h] == s + 1);
    unsigned long long m = __ballot(valid[c]);
    if (lane == 0) wtot[c * 4 + w] = __popcll(m);
  }
  __syncthreads();

  // Every thread computes the 16-entry exclusive prefix (trivial).
  int pre[16];
  int run = 0;
#pragma unroll
  for (int i = 0; i < 16; ++i) { pre[i] = run; run += wtot[i]; }
  const int count = run;
  const int keff = count < NL ? count : NL;
  const int offset = count - keff;     // max(count - L, 0)

  if (t == 0) {
    kept_eff[g] = keff;
    sbase = atomicAdd(n_rows, keff);
  }
  __syncthreads();
  const int base = sbase;

  // Pass 2: assign ranks and emit kept rows.
  const unsigned long long lt = (1ull << lane) - 1ull;
#pragma unroll
  for (int c = 0; c < 4; ++c) {
    unsigned long long m = __ballot(valid[c]);
    if (valid[c]) {
      int rank = pre[c * 4 + w] + __popcll(m & lt);
      if (rank >= offset) {
        int slot = rank - offset;
        row_src[base + slot] = b * NH + c * 256 + t;
        row_dst[base + slot] = g * NL + slot;
      }
    }
  }
}

// ---------------------------------------------------------------------------
// K2: f32 [K,N] -> bf16 [N,K] tiled transpose (weights).
// ---------------------------------------------------------------------------
template <int KD, int NDIM>
__global__ void transpose_cvt_kernel(const float* __restrict__ src,
                                     bf16_t* __restrict__ dst) {
  __shared__ float tile[32][33];
  int k0 = blockIdx.y * 32, n0 = blockIdx.x * 32;
  int tx = threadIdx.x & 31, ty = threadIdx.x >> 5;   // 32 x 8
#pragma unroll
  for (int i = 0; i < 32; i += 8)
    tile[ty + i][tx] = src[(size_t)(k0 + ty + i) * NDIM + n0 + tx];
  __syncthreads();
#pragma unroll
  for (int i = 0; i < 32; i += 8)
    dst[(size_t)(n0 + ty + i) * KD + k0 + tx] = (bf16_t)tile[tx][ty + i];
}

// ---------------------------------------------------------------------------
// K3: gather 5 f32 embeddings + LayerNorm -> bf16 X[r_local, 2560]
// One block (256 threads) per compact row in this chunk.
// ---------------------------------------------------------------------------
__global__ void gather_ln_kernel(const float* __restrict__ embed,
                                 const float* __restrict__ tg_emb,
                                 const int* __restrict__ ht,
                                 const int* __restrict__ pt,
                                 const int* __restrict__ at,
                                 const int* __restrict__ ct,
                                 const int* __restrict__ tg,
                                 const float* __restrict__ gamma,
                                 const float* __restrict__ beta,
                                 const int* __restrict__ n_rows,
                                 const int* __restrict__ row_src,
                                 int row_base,
                                 bf16_t* __restrict__ X) {
  int rl = blockIdx.x;
  int r = row_base + rl;
  if (r >= *n_rows) return;
  int pos = row_src[r];
  int t = threadIdx.x;

  const float* seg[5];
  seg[0] = embed + (size_t)ht[pos] * ND;
  seg[1] = embed + (size_t)pt[pos] * ND;
  seg[2] = embed + (size_t)at[pos] * ND;
  seg[3] = embed + (size_t)ct[pos] * ND;
  int tgv = tg[pos];
  tgv = tgv < 0 ? 0 : (tgv > 128 ? 128 : tgv);
  seg[4] = tg_emb + (size_t)tgv * ND;

  float v[10];
  float sum = 0.f, sq = 0.f;
#pragma unroll
  for (int i = 0; i < 10; ++i) {
    int c = t + i * 256;                 // 0..2559; c>>9 constant per i
    v[i] = seg[c >> 9][c & 511];
    sum += v[i];
    sq += v[i] * v[i];
  }
#pragma unroll
  for (int off = 32; off > 0; off >>= 1) {
    sum += __shfl_down(sum, off);
    sq += __shfl_down(sq, off);
  }
  __shared__ float red[8];
  int wv = t >> 6, ln = t & 63;
  if (ln == 0) { red[wv] = sum; red[4 + wv] = sq; }
  __syncthreads();
  float S = red[0] + red[1] + red[2] + red[3];
  float Q = red[4] + red[5] + red[6] + red[7];
  float mu = S * (1.f / FIVE_D);
  float var = Q * (1.f / FIVE_D) - mu * mu;
  float rstd = rsqrtf(var + 1e-5f);

  bf16_t* xr = X + (size_t)rl * FIVE_D;
#pragma unroll
  for (int i = 0; i < 10; ++i) {
    int c = t + i * 256;
    xr[c] = (bf16_t)((v[i] - mu) * rstd * gamma[c] + beta[c]);
  }
}

// ---------------------------------------------------------------------------
// MFMA GEMM (m97 structure): C[M,N] = A[M,KD] @ Bt[N,KD]^T.
// global_load_lds DMA staging, 128x128 tile, BK=32, 4 waves, 16x16x32 bf16.
// EPI=1: +bias, SiLU -> bf16 Cb[rows][LDC].
// EPI=2: +bias +pos_emb +seq_emb, scatter f32 rows via row_dst into out.
// ---------------------------------------------------------------------------
template <int KD, int LDC, int EPI>
__launch_bounds__(256)
__global__ void gemm_kernel(const bf16_t* __restrict__ A,
                            const bf16_t* __restrict__ Bt,
                            const int* __restrict__ nrows_p,
                            int row_base,
                            const float* __restrict__ bias,
                            bf16_t* __restrict__ Cb,
                            const int* __restrict__ row_dst,
                            const float* __restrict__ pos_emb,
                            const float* __restrict__ seq_emb,
                            float* __restrict__ out) {
  const int M = *nrows_p;
  const int m0 = blockIdx.y * 128;                 // local row base
  if (row_base + m0 >= M) return;
  const int n0 = blockIdx.x * 128;

  __shared__ bf16_t As[128 * 32];
  __shared__ bf16_t Bs[128 * 32];

  const int t = threadIdx.x;
  const int lane = t & 63;
  const int wave = t >> 6;
  const int wm = wave >> 1;
  const int wn = wave & 1;
  const int l15 = lane & 15;
  const int l4 = lane >> 4;

  f32x4 acc[4][4] = {};

  const int r0 = t >> 2;            // tile row for this thread's 16B segment
  const int kq = (t & 3) * 8;       // bf16 offset within 32-wide k window
  const bf16_t* Ag0 = A + (size_t)(m0 + r0) * KD + kq;
  const bf16_t* Ag1 = A + (size_t)(m0 + 64 + r0) * KD + kq;
  const bf16_t* Bg0 = Bt + (size_t)(n0 + r0) * KD + kq;
  const bf16_t* Bg1 = Bt + (size_t)(n0 + 64 + r0) * KD + kq;
  bf16_t* Al0 = As + t * 8;
  bf16_t* Al1 = As + (t + 256) * 8;
  bf16_t* Bl0 = Bs + t * 8;
  bf16_t* Bl1 = Bs + (t + 256) * 8;

  for (int k0 = 0; k0 < KD; k0 += 32) {
    __syncthreads();
    async_ld16(Ag0 + k0, Al0);
    async_ld16(Ag1 + k0, Al1);
    async_ld16(Bg0 + k0, Bl0);
    async_ld16(Bg1 + k0, Bl1);
    __syncthreads();

    bf16x8 af[4], bfr[4];
#pragma unroll
    for (int i = 0; i < 4; ++i)
      af[i] = *(const bf16x8*)(As + (wm * 64 + i * 16 + l15) * 32 + l4 * 8);
#pragma unroll
    for (int i = 0; i < 4; ++i)
      bfr[i] = *(const bf16x8*)(Bs + (wn * 64 + i * 16 + l15) * 32 + l4 * 8);
#pragma unroll
    for (int i = 0; i < 4; ++i)
#pragma unroll
      for (int j = 0; j < 4; ++j)
        acc[i][j] =
            __builtin_amdgcn_mfma_f32_16x16x32_bf16(af[i], bfr[j], acc[i][j], 0, 0, 0);
  }

  if constexpr (EPI == 1) {
#pragma unroll
    for (int i = 0; i < 4; ++i) {
      int mbase = m0 + wm * 64 + i * 16 + l4 * 4;   // local row
#pragma unroll
      for (int j = 0; j < 4; ++j) {
        int n = n0 + wn * 64 + j * 16 + l15;
        float bn = bias[n];
#pragma unroll
        for (int q = 0; q < 4; ++q) {
          float v = acc[i][j][q] + bn;
          v = v / (1.f + __expf(-v));              // SiLU
          Cb[(size_t)(mbase + q) * LDC + n] = (bf16_t)v;
        }
      }
    }
  } else {
#pragma unroll
    for (int i = 0; i < 4; ++i) {
      int mbase = m0 + wm * 64 + i * 16 + l4 * 4;   // local row
#pragma unroll
      for (int q = 0; q < 4; ++q) {
        int r = mbase + q;                          // local row
        if (row_base + r >= M) continue;
        int dst = row_dst[row_base + r];            // (b*S+s)*L + slot
        int slot = dst & (NL - 1);
        int sg = (dst >> 8) & 3;
#pragma unroll
        for (int j = 0; j < 4; ++j) {
          int n = n0 + wn * 64 + j * 16 + l15;
          float v = acc[i][j][q] + bias[n] + pos_emb[slot * ND + n] +
                    seq_emb[(sg + 1) * ND + n];
          out[(size_t)dst * ND + n] = v;            // f32 output
        }
      }
    }
  }
}

// ---------------------------------------------------------------------------
// K5: background fill (f32) — zeros for unkept slots, empty-group slot 0,
// and the f32 sequence mask. One block per (b, s).
// ---------------------------------------------------------------------------
__global__ void fill_bg_kernel(const int* __restrict__ kept_eff,
                               const float* __restrict__ empty_tokens,
                               const float* __restrict__ pos_emb,
                               const float* __restrict__ seq_emb,
                               float* __restrict__ out,
                               float* __restrict__ mask) {
  int g = blockIdx.x;              // b*S + s
  int s = g & 3;
  int t = threadIdx.x;
  int ce = kept_eff[g];            // min(count, L)
  bool empty = (ce == 0);
  int keptm = empty ? 1 : ce;

  mask[g * NL + t] = (t < keptm) ? 1.f : 0.f;      // t in [0,256)=L

  float* base = out + (size_t)g * NL * ND;
  if (empty) {
    for (int d = t; d < ND; d += 256)
      base[d] = empty_tokens[s * ND + d] + pos_emb[d] + seq_emb[(s + 1) * ND + d];
  }
  int start = empty ? 1 : ce;
  // zero-fill slots [start, 256) with 16B stores
  uint4* p = (uint4*)base;         // 4 f32 per uint4; one slot = 128 uint4
  uint4 z; z.x = z.y = z.z = z.w = 0u;
  for (int i = start * (ND / 4) + t; i < NL * (ND / 4); i += 256) p[i] = z;
}

// ---------------------------------------------------------------------------
extern "C" void kernel_launch(void* const* d_in, const int* in_sizes, int n_in,
                              void* d_out, int out_size, void* d_ws,
                              size_t ws_size, hipStream_t stream) {
  const float* embed_table = (const float*)d_in[0];
  const float* time_gap_emb = (const float*)d_in[1];
  const float* seq_id_emb = (const float*)d_in[2];
  const float* pos_emb = (const float*)d_in[3];
  const float* ln_gamma = (const float*)d_in[4];
  const float* ln_beta = (const float*)d_in[5];
  const float* w1 = (const float*)d_in[6];
  const float* b1 = (const float*)d_in[7];
  const float* w2 = (const float*)d_in[8];
  const float* b2 = (const float*)d_in[9];
  const float* empty_tokens = (const float*)d_in[10];
  const int* history_tokens = (const int*)d_in[11];
  const int* post_tokens = (const int*)d_in[12];
  const int* author_tokens = (const int*)d_in[13];
  const int* action_tokens = (const int*)d_in[14];
  const int* time_gap = (const int*)d_in[15];
  const int* group_ids = (const int*)d_in[16];
  const int* lengths = (const int*)d_in[17];

  // Workspace (~88 MB peak)
  char* ws = (char*)d_ws;
  int* n_rows = (int*)ws;                                  // 4 B
  int* kept_eff = (int*)(ws + 256);                        // 128*4 B
  int* row_src = (int*)(ws + 4096);                        // 32768*4 B
  int* row_dst = (int*)(ws + 4096 + 131072);               // 32768*4 B
  bf16_t* W1T = (bf16_t*)(ws + 266240);                    // [2048][2560] bf16
  bf16_t* W2T = W1T + (size_t)HID * FIVE_D;                // [512][2048]  bf16
  bf16_t* Xc = W2T + (size_t)ND * HID;                     // [CHUNK][2560] bf16
  bf16_t* H1c = Xc + (size_t)CHUNK * FIVE_D;               // [CHUNK][2048] bf16

  float* out_states = (float*)d_out;                       // f32 output
  float* out_mask = out_states + (size_t)NB * NS * NL * ND;

  // n_rows must start at 0 (ws is poisoned 0xAA before every launch).
  hipMemsetAsync(n_rows, 0, 4, stream);

  build_index_kernel<<<NB * NS, 256, 0, stream>>>(group_ids, lengths, n_rows,
                                                  kept_eff, row_src, row_dst);

  transpose_cvt_kernel<FIVE_D, HID>
      <<<dim3(HID / 32, FIVE_D / 32), 256, 0, stream>>>(w1, W1T);
  transpose_cvt_kernel<HID, ND>
      <<<dim3(ND / 32, HID / 32), 256, 0, stream>>>(w2, W2T);

  for (int c = 0; c < NCHUNK; ++c) {
    int row_base = c * CHUNK;
    gather_ln_kernel<<<CHUNK, 256, 0, stream>>>(
        embed_table, time_gap_emb, history_tokens, post_tokens, author_tokens,
        action_tokens, time_gap, ln_gamma, ln_beta, n_rows, row_src, row_base,
        Xc);

    gemm_kernel<FIVE_D, HID, 1>
        <<<dim3(HID / 128, CHUNK / 128), 256, 0, stream>>>(
            Xc, W1T, n_rows, row_base, b1, H1c, nullptr, nullptr, nullptr,
            nullptr);

    gemm_kernel<HID, ND, 2>
        <<<dim3(ND / 128, CHUNK / 128), 256, 0, stream>>>(
            H1c, W2T, n_rows, row_base, b2, nullptr, row_dst, pos_emb,
            seq_id_emb, out_states);
  }

  fill_bg_kernel<<<NB * NS, 256, 0, stream>>>(kept_eff, empty_tokens, pos_emb,
                                              seq_id_emb, out_states, out_mask);
}